// Round 4
// baseline (943.476 us; speedup 1.0000x reference)
//
#include <hip/hip_runtime.h>
#include <stdint.h>

#define NB 16      // batch
#define TT 4096    // seq len
#define DD 512     // dim
#define CC 32      // chunk size
#define MM 64      // mem slots
#define NCH 128    // number of chunks
#define NSRC 192   // 64 init + 128 newm sources
#define ROWW 36    // Gx row stride floats: 32 logits + 1 NN + 3 pad
#define TOTROWS 16320  // sum_{t=0}^{127} (64+t)
#define KS 32      // k-step for k2 GEMM

// ws float-offsets
#define WS_NEWM 0
#define WS_NN2  (NB*NCH*DD)                 // 1,048,576
#define WS_GX   (WS_NN2 + NB*NCH)           // 1,050,624
#define WS_CTL  (WS_GX + (size_t)NB*TOTROWS*ROWW)   // 10,450,944 (floats)

__device__ __forceinline__ float wredsum(float v){
#pragma unroll
  for (int o = 32; o > 0; o >>= 1) v += __shfl_xor(v, o);
  return v;
}
__device__ __forceinline__ float wredmax(float v){
#pragma unroll
  for (int o = 32; o > 0; o >>= 1) v = fmaxf(v, __shfl_xor(v, o));
  return v;
}

// ======================= K1: maxpool new_m + ||new_m||^2 =======================
__global__ __launch_bounds__(256)
void k1_newm(const float* __restrict__ x, float* __restrict__ ws)
{
  __shared__ float part[4];
  const int bid = blockIdx.x;
  const int b = bid >> 7, t = bid & 127;
  const int tid = threadIdx.x;
  const float* xb = x + ((size_t)b*TT + (size_t)t*CC)*DD;
  const int k0 = tid*2;
  float v0 = -INFINITY, v1 = -INFINITY;
#pragma unroll
  for (int c = 0; c < CC; ++c){
    const float2 xv = *(const float2*)(xb + (size_t)c*DD + k0);
    v0 = fmaxf(v0, xv.x); v1 = fmaxf(v1, xv.y);
  }
  float* nm = ws + WS_NEWM + ((size_t)b*NCH + t)*DD;
  nm[k0] = v0; nm[k0+1] = v1;
  float p = wredsum(v0*v0 + v1*v1);
  if ((tid & 63) == 0) part[tid >> 6] = p;
  __syncthreads();
  if (tid == 0) ws[WS_NN2 + (size_t)b*NCH + t] = part[0]+part[1]+part[2]+part[3];
}

// ======================= K2: tiled GEMM  G = X . S^T  =======================
__global__ __launch_bounds__(512)
void k2_gemm(const float* __restrict__ x, const float* __restrict__ mem_init,
             float* __restrict__ ws)
{
  __shared__ float Xs[KS][128];      // [k][token] 16 KB
  __shared__ float Ss[KS][NSRC];     // [k][row]   24 KB

  const int b  = blockIdx.x;
  const int tg = blockIdx.y;
  const int tid = threadIdx.x;
  const int rowlim = min(NSRC, 68 + 4*tg);
  const int T0 = tg*128;

  const int ot = tid & 15;           // token octet (8 tokens)
  const int rs = tid >> 4;           // row sextet (6 rows), 0..31
  const bool active = (rs*6 < rowlim);

  float acc[6][8];
#pragma unroll
  for (int j = 0; j < 6; ++j)
#pragma unroll
    for (int i = 0; i < 8; ++i) acc[j][i] = 0.0f;

  const float* xb    = x + ((size_t)b*TT + T0)*DD;
  const float* nmarr = ws + WS_NEWM + (size_t)b*NCH*DD;

  const int xtok = tid >> 2;
  const int xkq  = tid & 3;
  const int srow = tid >> 1;
  const int shalf= tid & 1;
  const float* srcrow = nullptr;
  if (tid < 384 && srow < rowlim)
    srcrow = (srow < MM) ? (mem_init + ((size_t)b*MM + srow)*DD)
                         : (nmarr + (size_t)(srow - MM)*DD);

  for (int ks = 0; ks < DD/KS; ++ks){
    const int k0 = ks*KS;
    {
      const float* p = xb + (size_t)xtok*DD + k0 + xkq*8;
      const float4 a  = *(const float4*)p;
      const float4 c4 = *(const float4*)(p + 4);
      const int kb = xkq*8;
      Xs[kb+0][xtok]=a.x;  Xs[kb+1][xtok]=a.y;  Xs[kb+2][xtok]=a.z;  Xs[kb+3][xtok]=a.w;
      Xs[kb+4][xtok]=c4.x; Xs[kb+5][xtok]=c4.y; Xs[kb+6][xtok]=c4.z; Xs[kb+7][xtok]=c4.w;
    }
    if (srcrow){
      const float* p = srcrow + k0 + shalf*16;
#pragma unroll
      for (int q = 0; q < 4; ++q){
        const float4 a = *(const float4*)(p + q*4);
        const int kb = shalf*16 + q*4;
        Ss[kb+0][srow]=a.x; Ss[kb+1][srow]=a.y; Ss[kb+2][srow]=a.z; Ss[kb+3][srow]=a.w;
      }
    }
    __syncthreads();
    if (active){
#pragma unroll
      for (int k = 0; k < KS; ++k){
        const float4 x0 = *(const float4*)&Xs[k][ot*8];
        const float4 x1 = *(const float4*)&Xs[k][ot*8 + 4];
        const float2 r0 = *(const float2*)&Ss[k][rs*6];
        const float2 r1 = *(const float2*)&Ss[k][rs*6 + 2];
        const float2 r2 = *(const float2*)&Ss[k][rs*6 + 4];
        const float xv[8] = {x0.x,x0.y,x0.z,x0.w,x1.x,x1.y,x1.z,x1.w};
        const float rv[6] = {r0.x,r0.y,r1.x,r1.y,r2.x,r2.y};
#pragma unroll
        for (int j = 0; j < 6; ++j)
#pragma unroll
          for (int i = 0; i < 8; ++i)
            acc[j][i] = fmaf(rv[j], xv[i], acc[j][i]);
      }
    }
    __syncthreads();
  }

  const float inv_sqrt_d = 1.0f / sqrtf((float)DD);
  const int t  = tg*4 + (ot >> 2);
  const int c0 = (ot & 3)*8;
  float* gbase = ws + WS_GX + ((size_t)b*TOTROWS + (size_t)(64*t + (t*(t-1))/2))*ROWW;
#pragma unroll
  for (int j = 0; j < 6; ++j){
    const int row = rs*6 + j;
    if (row < 64 + t){
      float* g = gbase + (size_t)row*ROWW + c0;
      float4 o0 = {acc[j][0]*inv_sqrt_d, acc[j][1]*inv_sqrt_d,
                   acc[j][2]*inv_sqrt_d, acc[j][3]*inv_sqrt_d};
      float4 o1 = {acc[j][4]*inv_sqrt_d, acc[j][5]*inv_sqrt_d,
                   acc[j][6]*inv_sqrt_d, acc[j][7]*inv_sqrt_d};
      *(float4*)g = o0;
      *(float4*)(g + 4) = o1;
    }
  }
}

// ======================= K2b: NN column  grow[32] = newm_t . src_row =======================
__global__ __launch_bounds__(256)
void k2_nn(const float* __restrict__ mem_init, float* __restrict__ ws)
{
  __shared__ float nm[DD];
  const int b = blockIdx.x, t = blockIdx.y;
  const int tid = threadIdx.x, lane = tid & 63, w = tid >> 6;
  const float* nmarr = ws + WS_NEWM + (size_t)b*NCH*DD;
  {
    const float2 v = *(const float2*)(nmarr + (size_t)t*DD + tid*2);
    nm[tid*2] = v.x; nm[tid*2+1] = v.y;
  }
  __syncthreads();
  const float4 na = *(const float4*)(nm + lane*8);
  const float4 nc = *(const float4*)(nm + lane*8 + 4);
  const int nrows = MM + t;
  float* gbase = ws + WS_GX + ((size_t)b*TOTROWS + (size_t)(64*t + (t*(t-1))/2))*ROWW;
  for (int r = w; r < nrows; r += 4){
    const float* src = (r < MM) ? (mem_init + ((size_t)b*MM + r)*DD)
                                : (nmarr + (size_t)(r - MM)*DD);
    const float4 a  = *(const float4*)(src + lane*8);
    const float4 c4 = *(const float4*)(src + lane*8 + 4);
    float d = a.x*na.x + a.y*na.y + a.z*na.z + a.w*na.w
            + c4.x*nc.x + c4.y*nc.y + c4.z*nc.z + c4.w*nc.w;
    d = wredsum(d);
    if (lane == 0) gbase[(size_t)r*ROWW + 32] = d;
  }
}

// ======================= K3: speculative pipelined scan =======================
// At iteration t: apply d(t-1); compute idx1/idx2(t); build E(t+1) with BOTH
// one-column variants; precompute both candidate entropies/scores for t+1;
// spin for step-t entropies -> d(t) -> publish selected ent(t+1) immediately.
__global__ __launch_bounds__(1024)
void k3_scan(const float* __restrict__ mem_init, float* __restrict__ ws,
             float* __restrict__ out)
{
  __shared__ float Llds[CC][65];       // logits for t+1 (base)
  __shared__ float Elds[CC][65];       // exp(logits - mx)
  __shared__ float P1[16][65];         // matvec partials variant1
  __shared__ float P2[16][65];         // variant2
  __shared__ float dense[MM][NSRC];    // coef rows for complex slots
  __shared__ float S_base[CC], Mx[CC], E1c[CC], E2c[CC], R1[CC], R2[CC];
  __shared__ float s_sc[MM], s_fr[MM], s_n2[MM];
  __shared__ float s_sdB[MM];          // gathered base NN (for step t+1)
  __shared__ float s_sdCur[MM];        // simdot at current step t
  __shared__ float s_scoreP[MM], s_scoreC[MM];
  __shared__ int   s_srcRow[MM], s_isC[MM];
  __shared__ float s_rnmNN, s_sd1v, s_sd2v, s_n2v1, s_n2v2;
  __shared__ int   s_d, s_i1p, s_i2p, s_oldC2, s_oldR2;

  const int tid  = threadIdx.x;
  const int lane = tid & 63;
  const int w    = tid >> 6;
  const int b    = blockIdx.x;
  const int wu   = __builtin_amdgcn_readfirstlane(w);

  const float* newmarr = ws + WS_NEWM;
  const float* nn2arr  = ws + WS_NN2;
  const float* gx      = ws + WS_GX;
  unsigned long long* ctl = (unsigned long long*)(ws + WS_CTL); // [parity*16 + b]

  const int  gm  = tid >> 4;          // gather column (slot m)
  const int  gc2 = (tid & 15)*2;      // gather c pair
  const bool gl  = ((tid & 15) == 0);

  // ---- init state ----
  if (tid < MM){ s_sc[tid]=0.f; s_fr[tid]=0.f; s_srcRow[tid]=tid; s_isC[tid]=0; }
#pragma unroll
  for (int it = 0; it < 4; ++it){      // ||mem_init[m]||^2
    const int m0 = wu + it*16;
    const float* src = mem_init + ((size_t)b*MM + m0)*DD;
    const float4 a  = *(const float4*)(src + lane*8);
    const float4 c4 = *(const float4*)(src + lane*8 + 4);
    float p = a.x*a.x + a.y*a.y + a.z*a.z + a.w*a.w
            + c4.x*c4.x + c4.y*c4.y + c4.z*c4.z + c4.w*c4.w;
    p = wredsum(p);
    if (lane == 0) s_n2[m0] = p;
  }
  __syncthreads();

  // ---- prologue: build step-0 logits/score/entropy and publish ----
  {
    const float* gx0 = gx + (size_t)b*TOTROWS*ROWW;
    const float* grow = gx0 + (size_t)gm*ROWW;      // srcRow = identity
    const float2 p = *(const float2*)(grow + gc2);
    Llds[gc2][gm] = p.x; Llds[gc2+1][gm] = p.y;
    if (gl) s_sdCur[gm] = grow[32];
  }
  __syncthreads();
  { // exp pass: wave wu -> rows 2wu, 2wu+1
#pragma unroll
    for (int rr = 0; rr < 2; ++rr){
      const int c = 2*wu + rr;
      const float l = Llds[c][lane];
      const float mx = wredmax(l);
      const float e = expf(l - mx);
      const float S = wredsum(e);
      Elds[c][lane] = e;
      if (lane == 0){ S_base[c] = S; Mx[c] = mx; }
    }
  }
  __syncthreads();
  { // base matvec
    const int m = tid & 63, g = tid >> 6;
    const int c0 = 2*g, c1 = c0 + 1;
    P1[g][m] = Elds[c0][m]/S_base[c0] + Elds[c1][m]/S_base[c1];
  }
  __syncthreads();
  if (wu == 0){
    float s0 = 0.f;
#pragma unroll
    for (int g = 0; g < 16; ++g) s0 += P1[g][lane];
    s0 *= 0.03125f;
    s_scoreC[lane] = s0;
    const float ent0 = wredsum(-log2f(s0 + 1e-10f) * s0);
    if (lane == 0){
      const unsigned long long v = ((unsigned long long)1u << 32)
                                 | (unsigned long long)__float_as_uint(ent0);
      __hip_atomic_store(&ctl[b], v, __ATOMIC_RELEASE, __HIP_MEMORY_SCOPE_AGENT);
    }
  }
  __syncthreads();

  // ---- main loop ----
  for (int t = 0; t < NCH; ++t){
    const float nn2_t = nn2arr[(size_t)b*NCH + t];

    // ---- apply decision d(t-1) ----
    if (t > 0){
      const int d = s_d;
      const int m1 = s_i1p, m2 = s_i2p;
      if (d){
        if (tid < MM){
          float ns = s_sc[tid] + s_scoreP[tid];
          float nf = s_fr[tid] + 1.0f;
          if (tid == m1){ ns = 0.0f; nf = 1.0f; }
          s_sc[tid] = ns; s_fr[tid] = nf;
          s_sdCur[tid] = (tid == m1) ? s_sd1v : s_sdB[tid];
        }
        if (tid == 512){
          s_srcRow[m1] = 64 + (t-1);
          s_isC[m1] = 0;
          s_n2[m1] = s_n2v1;
        }
      } else {
        if (tid < NSRC){
          float val = s_oldC2 ? 0.3f*dense[m2][tid] : ((tid == s_oldR2) ? 0.3f : 0.0f);
          if (tid == 64 + (t-1)) val += 0.7f;
          dense[m2][tid] = val;
        }
        if (tid < MM) s_sdCur[tid] = (tid == m2) ? s_sd2v : s_sdB[tid];
        if (tid == 512){
          s_isC[m2] = 1;
          s_n2[m2] = s_n2v2;
        }
      }
    }
    __syncthreads();   // B1

    // ---- gather L(t+1) base + newm-row (skip last) ----
    if (t < NCH-1){
      const float* gxn = gx + ((size_t)b*TOTROWS
                         + (size_t)(64*(t+1) + ((t+1)*t)/2))*ROWW;
      float v0, v1, sd = 0.f;
      if (!s_isC[gm]){
        const float* grow = gxn + (size_t)s_srcRow[gm]*ROWW;
        const float2 p = *(const float2*)(grow + gc2);
        v0 = p.x; v1 = p.y;
        if (gl) sd = grow[32];
      } else {
        v0 = 0.f; v1 = 0.f;
        const int ns = 65 + t;
        for (int s2 = 0; s2 < ns; ++s2){
          const float co = dense[gm][s2];
          if (co != 0.0f){
            const float* grow = gxn + (size_t)s2*ROWW;
            v0 = fmaf(co, grow[gc2],   v0);
            v1 = fmaf(co, grow[gc2+1], v1);
            if (gl) sd = fmaf(co, grow[32], sd);
          }
        }
      }
      Llds[gc2][gm] = v0; Llds[gc2+1][gm] = v1;
      if (gl) s_sdB[gm] = sd;
      if (tid < 32) { // reuse Mx slot? no: rnm values go via E1c? keep in Llds pad? -> dedicated loads below
        // newm-row logits (row 64+t of table t+1)
        // stored into the padding column of Llds (index 64) to save LDS:
        Llds[tid][64] = gxn[(size_t)(64+t)*ROWW + tid];
      }
      if (tid == 32) s_rnmNN = gxn[(size_t)(64+t)*ROWW + 32];
    }
    __syncthreads();   // B2

    // ---- argmin/argmax + exp pass ----
    if (wu == 0){
      float q = (s_sc[lane] + s_scoreC[lane]) / (s_fr[lane] + 1.0f);
      int idx = lane;
#pragma unroll
      for (int o = 32; o > 0; o >>= 1){
        const float ov = __shfl_xor(q, o);
        const int   oi = __shfl_xor(idx, o);
        if (ov < q || (ov == q && oi < idx)){ q = ov; idx = oi; }
      }
      if (lane == 0) s_i1p = idx;
      if (t < NCH-1){
#pragma unroll
        for (int rr = 0; rr < 2; ++rr){
          const int c = 28 + rr;
          const float l = Llds[c][lane];
          const float mx = wredmax(l);
          const float e = expf(l - mx);
          const float S = wredsum(e);
          Elds[c][lane] = e;
          if (lane == 0){ S_base[c] = S; Mx[c] = mx; }
        }
      }
    } else if (wu == 1){
      float sim = s_sdCur[lane] / (sqrtf(nn2_t + 1e-8f) * sqrtf(s_n2[lane] + 1e-8f));
      int idx = lane;
#pragma unroll
      for (int o = 32; o > 0; o >>= 1){
        const float ov = __shfl_xor(sim, o);
        const int   oi = __shfl_xor(idx, o);
        if (ov > sim || (ov == sim && oi < idx)){ sim = ov; idx = oi; }
      }
      if (lane == 0){
        s_i2p = idx;
        s_oldC2 = s_isC[idx];
        s_oldR2 = s_srcRow[idx];
        s_n2v2 = 0.09f*s_n2[idx] + 0.42f*s_sdCur[idx] + 0.49f*nn2_t;
        s_n2v1 = nn2_t;
      }
      if (t < NCH-1){
#pragma unroll
        for (int rr = 0; rr < 2; ++rr){
          const int c = 30 + rr;
          const float l = Llds[c][lane];
          const float mx = wredmax(l);
          const float e = expf(l - mx);
          const float S = wredsum(e);
          Elds[c][lane] = e;
          if (lane == 0){ S_base[c] = S; Mx[c] = mx; }
        }
      }
    } else {
      if (t < NCH-1){
#pragma unroll
        for (int rr = 0; rr < 2; ++rr){
          const int c = 2*(wu-2) + rr;
          const float l = Llds[c][lane];
          const float mx = wredmax(l);
          const float e = expf(l - mx);
          const float S = wredsum(e);
          Elds[c][lane] = e;
          if (lane == 0){ S_base[c] = S; Mx[c] = mx; }
        }
      }
    }
    __syncthreads();   // B3

    // ---- patch columns for both variants ----
    if (t < NCH-1){
      if (wu == 0 && lane < 32){
        const int c = lane;
        const int m1 = s_i1p;
        const float e1 = expf(Llds[c][64] - Mx[c]);
        const float S1 = S_base[c] - Elds[c][m1] + e1;
        E1c[c] = e1; R1[c] = 1.0f / S1;
        if (c == 0) s_sd1v = s_rnmNN;
      } else if (wu == 1 && lane < 32){
        const int c = lane;
        const int m2 = s_i2p;
        const float l2 = 0.3f*Llds[c][m2] + 0.7f*Llds[c][64];
        const float e2 = expf(l2 - Mx[c]);
        const float S2 = S_base[c] - Elds[c][m2] + e2;
        E2c[c] = e2; R2[c] = 1.0f / S2;
        if (c == 0) s_sd2v = 0.3f*s_sdB[m2] + 0.7f*s_rnmNN;
      }
    }
    __syncthreads();   // B4

    // ---- matvec for both variants ----
    if (t < NCH-1){
      const int m = tid & 63, g = tid >> 6;
      const int c0 = 2*g, c1 = c0 + 1;
      const int m1 = s_i1p, m2 = s_i2p;
      const float ea0 = Elds[c0][m], ea1 = Elds[c1][m];
      const float p1 = ((m==m1)?E1c[c0]:ea0)*R1[c0] + ((m==m1)?E1c[c1]:ea1)*R1[c1];
      const float p2 = ((m==m2)?E2c[c0]:ea0)*R2[c0] + ((m==m2)?E2c[c1]:ea1)*R2[c1];
      P1[g][m] = p1;
      P2[g][m] = p2;
    }
    __syncthreads();   // B5

    // ---- wave0: reduce, entropies, spin, decide, publish, select ----
    if (wu == 0){
      float s1 = 0.f, s2 = 0.f, ent1 = 0.f, ent2 = 0.f;
      if (t < NCH-1){
#pragma unroll
        for (int g = 0; g < 16; ++g){ s1 += P1[g][lane]; s2 += P2[g][lane]; }
        s1 *= 0.03125f; s2 *= 0.03125f;
        ent1 = wredsum(-log2f(s1 + 1e-10f) * s1);
        ent2 = wredsum(-log2f(s2 + 1e-10f) * s2);
      }
      float ev = 0.f;
      if (lane < NB){
        unsigned long long vv;
        do {
          vv = __hip_atomic_load(&ctl[(t&1)*16 + lane], __ATOMIC_ACQUIRE,
                                 __HIP_MEMORY_SCOPE_AGENT);
        } while ((unsigned)(vv >> 32) != (unsigned)(t+1));
        ev = __uint_as_float((unsigned)vv);
      }
      const float tot = wredsum(ev);
      const int d = (tot * (1.0f/16.0f) > 3.0f) ? 1 : 0;  // thr = 0.5*log2(64+1e-10)
      if (t < NCH-1){
        if (lane == 0){
          const float entp = d ? ent1 : ent2;
          const unsigned long long v = ((unsigned long long)(unsigned)(t+2) << 32)
                                     | (unsigned long long)__float_as_uint(entp);
          __hip_atomic_store(&ctl[((t+1)&1)*16 + b], v, __ATOMIC_RELEASE,
                             __HIP_MEMORY_SCOPE_AGENT);
        }
        s_scoreP[lane] = s_scoreC[lane];
        s_scoreC[lane] = d ? s1 : s2;
      }
      if (lane == 0) s_d = d;
    }
    __syncthreads();   // B6
  }

  // ---- final apply d(127) (state only: srcRow/isC/dense) ----
  {
    const int d = s_d;
    if (d){
      if (tid == 0){ s_srcRow[s_i1p] = 64 + (NCH-1); s_isC[s_i1p] = 0; }
    } else {
      const int i = s_i2p;
      if (tid < NSRC){
        float val = s_oldC2 ? 0.3f*dense[i][tid] : ((tid == s_oldR2) ? 0.3f : 0.0f);
        if (tid == 64 + (NCH-1)) val += 0.7f;
        dense[i][tid] = val;
      }
      if (tid == 0) s_isC[i] = 1;
    }
  }
  __syncthreads();

  // ---- reconstruction ----
#pragma unroll
  for (int it = 0; it < 4; ++it){
    const int mo = wu + it*16;
    const int k0 = lane*8;
    float o8[8];
    if (!s_isC[mo]){
      const int row = s_srcRow[mo];
      const float* vec = (row < MM) ? (mem_init + ((size_t)b*MM + row)*DD)
                                    : (newmarr + ((size_t)b*NCH + (row - MM))*DD);
#pragma unroll
      for (int j = 0; j < 8; ++j) o8[j] = vec[k0 + j];
    } else {
#pragma unroll
      for (int j = 0; j < 8; ++j) o8[j] = 0.0f;
      for (int s = 0; s < NSRC; ++s){
        const float co = dense[mo][s];
        if (co != 0.0f){
          const float* vec = (s < MM) ? (mem_init + ((size_t)b*MM + s)*DD)
                                      : (newmarr + ((size_t)b*NCH + (s - MM))*DD);
#pragma unroll
          for (int j = 0; j < 8; ++j) o8[j] = fmaf(co, vec[k0 + j], o8[j]);
        }
      }
    }
    float* dst = out + ((size_t)b*MM + mo)*DD + k0;
#pragma unroll
    for (int j = 0; j < 8; ++j) dst[j] = o8[j];
  }
}

extern "C" void kernel_launch(void* const* d_in, const int* in_sizes, int n_in,
                              void* d_out, int out_size, void* d_ws, size_t ws_size,
                              hipStream_t stream)
{
  const float* x  = (const float*)d_in[0];
  const float* mi = (const float*)d_in[1];
  float* out = (float*)d_out;
  float* ws  = (float*)d_ws;
  hipLaunchKernelGGL(k1_newm, dim3(NB*NCH), dim3(256), 0, stream, x, ws);
  hipLaunchKernelGGL(k2_gemm, dim3(NB, 32), dim3(512), 0, stream, x, mi, ws);
  hipLaunchKernelGGL(k2_nn,   dim3(NB, NCH), dim3(256), 0, stream, mi, ws);
  hipLaunchKernelGGL(k3_scan, dim3(NB), dim3(1024), 0, stream, mi, ws, out);
}